// Round 12
// baseline (1477.079 us; speedup 1.0000x reference)
//
#include <hip/hip_runtime.h>
#include <math.h>

#define SEQL   45000
#define NBAT   2
#define CCH    32
#define NSEL   512
#define NHEAD  4
#define DKD    32
#define HDD    128
#define MLPD   512
#define CDCAP  2048
#define TKB    32     // scan slices per (b,channel)
#define ETB    176    // etab blocks = ceil(45000/256)

// bf16 helpers: round-to-nearest-even pack, cheap unpack (<<16)
__device__ __forceinline__ unsigned short f2bf(float x) {
  unsigned u = __float_as_uint(x);
  u = (u + 0x7fffu + ((u >> 16) & 1u)) >> 16;
  return (unsigned short)u;
}
#define BFL(u) __uint_as_float((u) << 16)
#define BFH(u) __uint_as_float((u) & 0xffff0000u)
#define U8F(w, s) ((float)(((w) >> (s)) & 0xffu))

// ---------------- K0: etab build (u8) + high16 hist + d_out zero ------------
__global__ __launch_bounds__(256) void prep_kernel(const float* __restrict__ att,
                                                   unsigned char* __restrict__ E,
                                                   int* __restrict__ hist,
                                                   float* __restrict__ out) {
  {
    int nthr = gridDim.x * 256;
    int gt = blockIdx.x * 256 + threadIdx.x;
    float4 z4 = make_float4(0.f, 0.f, 0.f, 0.f);
    float4* o4 = (float4*)out;
    for (int i = gt; i < NBAT * CCH * SEQL / 4; i += nthr) o4[i] = z4;
  }
  if (blockIdx.x < ETB) {
    int a = blockIdx.x * 256 + threadIdx.x;
    if (a >= SEQL) return;
    float ad = (float)a;
    float outv[16];
    float log2S = log2f((float)SEQL);
    #pragma unroll
    for (int k = 0; k < 5; ++k) {
      float hl = exp2f(3.0f + (float)k * (log2S - 3.0f) * 0.25f);
      outv[k] = exp2f(-ad / hl);
    }
    const int cw[5] = {1, 3, 7, 15, 31};
    #pragma unroll
    for (int k = 0; k < 5; ++k) outv[5 + k] = (a < cw[k]) ? 1.0f : 0.0f;
    float pmax = 0.0f;
    float pk[5];
    #pragma unroll
    for (int k = 0; k < 5; ++k) {
      float mean = 9000.0f * (float)(k + 1);
      float sd = 4500.0f;
      float cc = (mean / sd) * (mean / sd);      // 4,16,36,64,100
      float rr = mean / (sd * sd);
      float logz = lgammaf(cc) - cc * logf(rr);
      float pp;
      if (a == 0) pp = 1e-8f;                    // xlogy -> -inf -> exp = 0
      else pp = expf((cc - 1.0f) * logf(ad) - rr * ad - logz) + 1e-8f;
      pk[k] = pp;
      float mstar = (cc - 1.0f) / rr;            // 6750..44550, interior mode
      float m0 = floorf(mstar), m1 = m0 + 1.0f;
      if (m1 > (float)(SEQL - 1)) m1 = (float)(SEQL - 1);
      float p0 = expf((cc - 1.0f) * logf(m0) - rr * m0 - logz) + 1e-8f;
      float p1 = expf((cc - 1.0f) * logf(m1) - rr * m1 - logz) + 1e-8f;
      pmax = fmaxf(pmax, fmaxf(p0, p1));
    }
    #pragma unroll
    for (int k = 0; k < 5; ++k) outv[10 + k] = pk[k] / pmax;
    outv[15] = 0.0f;
    unsigned by[16];
    #pragma unroll
    for (int k = 0; k < 15; ++k)
      by[k] = (unsigned)(fminf(fmaxf(outv[k], 0.f), 1.f) * 255.f + 0.5f);
    by[15] = 0u;
    uint4 o;
    o.x = by[0]  | (by[1]  << 8) | (by[2]  << 16) | (by[3]  << 24);
    o.y = by[4]  | (by[5]  << 8) | (by[6]  << 16) | (by[7]  << 24);
    o.z = by[8]  | (by[9]  << 8) | (by[10] << 16) | (by[11] << 24);
    o.w = by[12] | (by[13] << 8) | (by[14] << 16);
    *(uint4*)(E + (size_t)a * 16) = o;
  } else {
    int bid = blockIdx.x - ETB;
    int ch4 = bid / TKB;
    int blk = bid % TKB;
    int b = ch4 >> 1, ch = ch4 & 1;
    const float* row = att + ((size_t)b * 3 + 1 + ch) * SEQL;
    int* h = hist + (size_t)ch4 * 65536;
    int per = (SEQL + TKB - 1) / TKB;
    int lo = blk * per;
    int hi = lo + per; if (hi > SEQL) hi = SEQL;
    for (int i = lo + threadIdx.x; i < hi; i += 256)
      atomicAdd(&h[__float_as_uint(row[i]) >> 16], 1);  // vals>=0 -> monotone
  }
}

// ---------------- K1: collect w/ inline threshold ---------------------------
__global__ __launch_bounds__(256) void topk_collect_kernel(
    const float* __restrict__ att, const int* __restrict__ hist,
    unsigned long long* __restrict__ cand, int* __restrict__ cnt) {
  __shared__ int s_scan[256];
  __shared__ int s_aux[2];
  int tid = threadIdx.x;
  int ch4 = blockIdx.x / TKB;
  int blk = blockIdx.x % TKB;
  const int* h = hist + (size_t)ch4 * 65536;
  {
    int base = tid * 256;
    int sum = 0;
    for (int i = 0; i < 64; ++i) {
      int4 v = ((const int4*)(h + base))[i];
      sum += v.x + v.y + v.z + v.w;
    }
    s_scan[tid] = sum;
  }
  __syncthreads();
  for (int d = 1; d < 256; d <<= 1) {
    int v = s_scan[tid] + ((tid + d < 256) ? s_scan[tid + d] : 0);
    __syncthreads();
    s_scan[tid] = v;
    __syncthreads();
  }
  {
    int sufEx = (tid == 255) ? 0 : s_scan[tid + 1];
    if (s_scan[tid] >= 256 && sufEx < 256) { s_aux[0] = tid; s_aux[1] = 256 - sufEx; }
  }
  __syncthreads();
  int chunk = s_aux[0], want = s_aux[1];
  s_scan[tid] = h[chunk * 256 + tid];
  __syncthreads();
  for (int d = 1; d < 256; d <<= 1) {
    int v = s_scan[tid] + ((tid + d < 256) ? s_scan[tid + d] : 0);
    __syncthreads();
    s_scan[tid] = v;
    __syncthreads();
  }
  {
    int sufEx2 = (tid == 255) ? 0 : s_scan[tid + 1];
    if (s_scan[tid] >= want && sufEx2 < want) s_aux[0] = chunk * 256 + tid;
  }
  __syncthreads();
  unsigned T16 = (unsigned)s_aux[0];
  int b = ch4 >> 1, ch = ch4 & 1;
  const float* row = att + ((size_t)b * 3 + 1 + ch) * SEQL;
  int per = (SEQL + TKB - 1) / TKB;
  int lo = blk * per;
  int hi = lo + per; if (hi > SEQL) hi = SEQL;
  for (int i = lo + tid; i < hi; i += 256) {
    unsigned key = __float_as_uint(row[i]);
    if ((key >> 16) >= T16) {
      int p = atomicAdd(&cnt[ch4], 1);
      if (p < CDCAP)
        cand[(size_t)ch4 * CDCAP + p] =
            ((unsigned long long)key << 32) | (unsigned)(~(unsigned)i);
    }
  }
}

// ---------------- K2a: per-channel desc sort -> top-256 (4 parallel blocks) -
// (un-fused from the merge: R5 showed fusing serialized two 45-stage bitonic
// sorts to save a 0.1us launch — a net loss)
__global__ __launch_bounds__(1024) void topk_sort_kernel(
    const unsigned long long* __restrict__ cand, const int* __restrict__ cnt,
    unsigned* __restrict__ chsel) {
  __shared__ unsigned long long sc[CDCAP];
  int ch4 = blockIdx.x, t = threadIdx.x;
  int n = cnt[ch4]; if (n > CDCAP) n = CDCAP;   // >=256 by construction
  int P = 256;
  while (P < n) P <<= 1;                        // typical 512
  for (int i = t; i < P; i += 1024)
    sc[i] = (i < n) ? cand[(size_t)ch4 * CDCAP + i] : 0ull;  // 0 sorts last
  __syncthreads();
  for (int k = 2; k <= P; k <<= 1) {
    for (int j = k >> 1; j > 0; j >>= 1) {
      for (int i = t; i < P; i += 1024) {
        int ixj = i ^ j;
        if (ixj > i) {
          unsigned long long va = sc[i], vb2 = sc[ixj];
          bool up = ((i & k) == 0);
          if ((va < vb2) == up) { sc[i] = vb2; sc[ixj] = va; }
        }
      }
      __syncthreads();
    }
  }
  // desc u64 = value desc, tie -> larger ~i = smaller index first
  if (t < 256)
    chsel[(size_t)ch4 * 256 + t] = ~(unsigned)(sc[t] & 0xFFFFFFFFull);
}

// ---------------- K2b: merge acc+don, ascending sort of 512 -----------------
__global__ __launch_bounds__(512) void topk_merge_kernel(const unsigned* __restrict__ chsel,
                                                         int* __restrict__ idx) {
  __shared__ int m[512];
  int b = blockIdx.x, tid = threadIdx.x;
  m[tid] = (int)chsel[(size_t)b * 512 + tid];
  __syncthreads();
  for (int k = 2; k <= 512; k <<= 1) {
    for (int j = k >> 1; j > 0; j >>= 1) {
      int ixj = tid ^ j;
      if (ixj > tid) {
        int va = m[tid], vb2 = m[ixj];
        bool up = ((tid & k) == 0);
        if ((va > vb2) == up) { m[tid] = vb2; m[ixj] = va; }
      }
      __syncthreads();
    }
  }
  idx[b * 512 + tid] = m[tid];
}

// ---------------- K3: fused gather + LN1 + QKV layer 0 ----------------------
// kbT/vT layout (bf16): [((b*4+h)*4+dpack)*4096 + i*8 + (d&7)]
__global__ __launch_bounds__(128) void gqkv0_kernel(
    const float* __restrict__ x, const int* __restrict__ idx,
    const float* __restrict__ ln_g, const float* __restrict__ ln_b,
    const float* __restrict__ Wq, const float* __restrict__ Wk,
    const float* __restrict__ Wv, const float* __restrict__ Wrel,
    const float* __restrict__ rcb, const float* __restrict__ rpb,
    float* __restrict__ emb, float* __restrict__ qc,
    unsigned short* __restrict__ kbT, unsigned short* __restrict__ vT,
    float* __restrict__ wb) {
  __shared__ float qs[128];
  const int l = 0;
  int hd = threadIdx.x;        // 0..127
  int hh = hd >> 5, d = hd & 31;
  int row = blockIdx.x;        // b*512 + i
  int b = row >> 9, ii = row & 511;
  int li = idx[b * NSEL + ii];
  float h[32];
  float mu = 0.f;
  #pragma unroll
  for (int c = 0; c < 32; ++c) {
    h[c] = x[((size_t)b * CCH + c) * SEQL + li];
    mu += h[c];
  }
  if (hd < 32) emb[(size_t)row * CCH + hd] = h[hd];
  mu *= (1.0f / 32.0f);
  float var = 0.f;
  #pragma unroll
  for (int c = 0; c < 32; ++c) { float dd0 = h[c] - mu; var += dd0 * dd0; }
  var *= (1.0f / 32.0f);
  float rstd = rsqrtf(var + 1e-5f);
  const float* g = ln_g + l * CCH;
  const float* bb = ln_b + l * CCH;
  #pragma unroll
  for (int c = 0; c < 32; ++c) h[c] = (h[c] - mu) * rstd * g[c] + bb[c];
  const float* wq = Wq + (size_t)l * CCH * HDD + hd;
  const float* wk = Wk + (size_t)l * CCH * HDD + hd;
  const float* wv = Wv + (size_t)l * CCH * HDD + hd;
  float q = 0.f, kk = 0.f, vv = 0.f;
  #pragma unroll
  for (int c = 0; c < 32; ++c) {
    q += h[c] * wq[c * HDD];
    kk += h[c] * wk[c * HDD];
    vv += h[c] * wv[c * HDD];
  }
  q *= 0.17677669529663687f;   // DK^-0.5
  qs[hd] = q;
  qc[(size_t)row * HDD + hd] = q + rcb[(l * NHEAD + hh) * DKD + d];
  size_t tpos = ((size_t)(b * 4 + hh) * 4 + (d >> 3)) * 4096 + (size_t)ii * 8 + (d & 7);
  kbT[tpos] = f2bf(kk);
  vT[tpos]  = f2bf(vv);
  __syncthreads();
  if (hd < 120) {
    int h2 = hd / 30, f = hd % 30;
    const float* wr = Wrel + ((size_t)l * 30 + f) * HDD + h2 * DKD;
    const float* rp = rpb + (l * NHEAD + h2) * DKD;
    const float* qsh = qs + h2 * DKD;
    float acc = 0.f;
    #pragma unroll
    for (int dd = 0; dd < 32; ++dd) acc += (qsh[dd] + rp[dd]) * wr[dd];
    wb[((size_t)row * NHEAD + h2) * 32 + f] = acc;   // padded stride 32
  }
}

// ---------------- K4: attention with LDS-staged k/v -------------------------
// 512 blocks (b, h, 8 rows), 4 waves x 2 sequential rows. Block stages the
// full head kT+vT (32+32 KB) into LDS once: k/v L2 traffic drops 8x (was one
// copy PER WAVE from L2 since 4 different (b,h) working sets blow L1).
// ds_read_b128 lane-consecutive 16B = 2-way bank aliasing = free.
// 66 KB LDS -> 2 blocks/CU co-resident.
__global__ __launch_bounds__(256, 2) void attn_kernel(
    const float* __restrict__ qc, const unsigned short* __restrict__ kbT,
    const unsigned short* __restrict__ vT, const float* __restrict__ wbuf,
    const unsigned char* __restrict__ E, const int* __restrict__ idx,
    float* __restrict__ ob) {
  __shared__ int idxl[512];
  __shared__ uint4 kls[2048];    // 32 KB: kT for this (b,h)
  __shared__ uint4 vls[2048];    // 32 KB: vT for this (b,h)
  int bid = blockIdx.x;
  int b = bid >> 8;
  int h = (bid >> 6) & 3;
  int i0 = (bid & 63) * 8;
  int tid = threadIdx.x;
  int wv = tid >> 6, ln = tid & 63;
  for (int i = tid; i < 512; i += 256) idxl[i] = idx[b * NSEL + i];
  {
    const uint4* kb4 = (const uint4*)kbT + (size_t)(b * 4 + h) * 2048;
    const uint4* vb4 = (const uint4*)vT + (size_t)(b * 4 + h) * 2048;
    for (int i = tid; i < 2048; i += 256) {
      kls[i] = kb4[i];
      vls[i] = vb4[i];
    }
  }
  __syncthreads();
  for (int itg = 0; itg < 2; ++itg) {
    int i = i0 + itg * 4 + wv;
    const float* qrow = qc + (size_t)(b * NSEL + i) * HDD + h * DKD;
    float q[32];
    #pragma unroll
    for (int d4 = 0; d4 < 8; ++d4) {
      float4 qv = *(const float4*)(qrow + d4 * 4);
      q[d4 * 4 + 0] = qv.x; q[d4 * 4 + 1] = qv.y;
      q[d4 * 4 + 2] = qv.z; q[d4 * 4 + 3] = qv.w;
    }
    const float* wrow = wbuf + ((size_t)(b * NSEL + i) * NHEAD + h) * 32;
    float w0[15], w1[15];
    #pragma unroll
    for (int f = 0; f < 15; ++f) {
      w0[f] = wrow[f] * (1.0f / 255.0f);        // u8 scale folded in
      w1[f] = wrow[15 + f] * (1.0f / 255.0f);
    }
    int ii = idxl[i];
    float lg[8];
    #pragma unroll
    for (int u = 0; u < 8; ++u) {
      int j = u * 64 + ln;
      int dj = ii - idxl[j];
      float cacc = 0.f;
      #pragma unroll
      for (int dp = 0; dp < 4; ++dp) {
        uint4 kv = kls[dp * 512 + j];
        cacc += q[dp * 8 + 0] * BFL(kv.x) + q[dp * 8 + 1] * BFH(kv.x)
              + q[dp * 8 + 2] * BFL(kv.y) + q[dp * 8 + 3] * BFH(kv.y)
              + q[dp * 8 + 4] * BFL(kv.z) + q[dp * 8 + 5] * BFH(kv.z)
              + q[dp * 8 + 6] * BFL(kv.w) + q[dp * 8 + 7] * BFH(kv.w);
      }
      int a = dj < 0 ? -dj : dj;
      uint4 e = *(const uint4*)(E + (size_t)a * 16);    // one 16B gather
      float r0 = U8F(e.x, 0)  * w0[0]  + U8F(e.x, 8)  * w0[1]
               + U8F(e.x, 16) * w0[2]  + U8F(e.x, 24) * w0[3]
               + U8F(e.y, 0)  * w0[4]  + U8F(e.y, 8)  * w0[5]
               + U8F(e.y, 16) * w0[6]  + U8F(e.y, 24) * w0[7]
               + U8F(e.z, 0)  * w0[8]  + U8F(e.z, 8)  * w0[9]
               + U8F(e.z, 16) * w0[10] + U8F(e.z, 24) * w0[11]
               + U8F(e.w, 0)  * w0[12] + U8F(e.w, 8)  * w0[13]
               + U8F(e.w, 16) * w0[14];
      float r1 = U8F(e.x, 0)  * w1[0]  + U8F(e.x, 8)  * w1[1]
               + U8F(e.x, 16) * w1[2]  + U8F(e.x, 24) * w1[3]
               + U8F(e.y, 0)  * w1[4]  + U8F(e.y, 8)  * w1[5]
               + U8F(e.y, 16) * w1[6]  + U8F(e.y, 24) * w1[7]
               + U8F(e.z, 0)  * w1[8]  + U8F(e.z, 8)  * w1[9]
               + U8F(e.z, 16) * w1[10] + U8F(e.z, 24) * w1[11]
               + U8F(e.w, 0)  * w1[12] + U8F(e.w, 8)  * w1[13]
               + U8F(e.w, 16) * w1[14];
      float sgn = dj > 0 ? 1.f : (dj < 0 ? -1.f : 0.f);
      lg[u] = cacc + r0 + sgn * r1;
    }
    // full-row softmax across the wave (512 logits, 8/lane), in registers
    float m = lg[0];
    #pragma unroll
    for (int u = 1; u < 8; ++u) m = fmaxf(m, lg[u]);
    #pragma unroll
    for (int s = 1; s < 64; s <<= 1) m = fmaxf(m, __shfl_xor(m, s));
    float ssum = 0.f;
    #pragma unroll
    for (int u = 0; u < 8; ++u) { lg[u] = __expf(lg[u] - m); ssum += lg[u]; }
    #pragma unroll
    for (int s = 1; s < 64; s <<= 1) ssum += __shfl_xor(ssum, s);
    float invs = 1.0f / ssum;
    // PV: p in registers, v from LDS; reduced-shuffle epilogue
    float* obrow = ob + (size_t)(b * NSEL + i) * HDD + h * DKD;
    #pragma unroll
    for (int dp = 0; dp < 4; ++dp) {
      float acc[8] = {0.f, 0.f, 0.f, 0.f, 0.f, 0.f, 0.f, 0.f};
      #pragma unroll
      for (int u = 0; u < 8; ++u) {
        uint4 vv = vls[dp * 512 + u * 64 + ln];
        float p = lg[u];
        acc[0] += p * BFL(vv.x); acc[1] += p * BFH(vv.x);
        acc[2] += p * BFL(vv.y); acc[3] += p * BFH(vv.y);
        acc[4] += p * BFL(vv.z); acc[5] += p * BFH(vv.z);
        acc[6] += p * BFL(vv.w); acc[7] += p * BFH(vv.w);
      }
      // octet-reduce all 8 accs (stages 1,2,4)
      #pragma unroll
      for (int s = 1; s < 8; s <<= 1) {
        #pragma unroll
        for (int t = 0; t < 8; ++t) acc[t] += __shfl_xor(acc[t], s);
      }
      // lane picks its d = ln&7, then cross-octet reduce (stages 8,16,32)
      int sel = ln & 7;
      float y = acc[0];
      #pragma unroll
      for (int t = 1; t < 8; ++t) y = (sel == t) ? acc[t] : y;
      #pragma unroll
      for (int s = 8; s < 64; s <<= 1) y += __shfl_xor(y, s);
      if (ln < 8) obrow[dp * 8 + ln] = y * invs;
    }
  }
}

// ---------------- K5: fused proj+res+LN2+MLP+res (2 rows) + qkv(l+1)/scatter
__global__ __launch_bounds__(256) void mlpqkv_kernel(
    const float* __restrict__ ob, const float* __restrict__ Wo,
    const float* __restrict__ bo,
    const float* __restrict__ ln2_g, const float* __restrict__ ln2_b,
    const float* __restrict__ W1, const float* __restrict__ b1,
    const float* __restrict__ W2, const float* __restrict__ b2,
    const float* __restrict__ ln1_g, const float* __restrict__ ln1_b,
    const float* __restrict__ Wq, const float* __restrict__ Wk,
    const float* __restrict__ Wv, const float* __restrict__ Wrel,
    const float* __restrict__ rcb, const float* __restrict__ rpb,
    const int* __restrict__ idx, float* __restrict__ emb,
    float* __restrict__ qc, unsigned short* __restrict__ kbT,
    unsigned short* __restrict__ vT, float* __restrict__ wb,
    float* __restrict__ out, int layer) {
  __shared__ float part[2][8][32];
  __shared__ float res[2][32];
  __shared__ float hln[2][32];
  __shared__ float fin[2][32];
  __shared__ float a1s[2][MLPD];
  __shared__ float qs[2][128];
  int row0 = blockIdx.x * 2;
  int tid = threadIdx.x;
  int c = tid & 31, seg = tid >> 5;
  const float* wo = Wo + (size_t)layer * HDD * CCH + c;
  float pacc[2] = {0.f, 0.f};
  #pragma unroll
  for (int k = 0; k < 16; ++k) {
    int kk = seg * 16 + k;
    float w = wo[kk * CCH];
    #pragma unroll
    for (int r = 0; r < 2; ++r)
      pacc[r] += ob[(size_t)(row0 + r) * HDD + kk] * w;
  }
  #pragma unroll
  for (int r = 0; r < 2; ++r) part[r][seg][c] = pacc[r];
  __syncthreads();
  if (tid < 64) {
    int r = tid >> 5, cc = tid & 31;
    float s = bo[layer * CCH + cc] + emb[(size_t)(row0 + r) * CCH + cc];
    #pragma unroll
    for (int sg = 0; sg < 8; ++sg) s += part[r][sg][cc];
    res[r][cc] = s;
  }
  __syncthreads();
  if (tid < 64) {
    int r = tid >> 5, cc = tid & 31;
    float mu = 0.f, s2 = 0.f;
    #pragma unroll
    for (int c2 = 0; c2 < 32; ++c2) { float v = res[r][c2]; mu += v; s2 += v * v; }
    mu *= (1.0f / 32.0f);
    float var = s2 * (1.0f / 32.0f) - mu * mu;
    float rstd = rsqrtf(var + 1e-5f);
    hln[r][cc] = (res[r][cc] - mu) * rstd * ln2_g[layer * CCH + cc] + ln2_b[layer * CCH + cc];
  }
  __syncthreads();
  const float* w1 = W1 + (size_t)layer * CCH * MLPD;
  float accA[2], accB[2];
  float bA = b1[layer * MLPD + tid], bB = b1[layer * MLPD + tid + 256];
  #pragma unroll
  for (int r = 0; r < 2; ++r) { accA[r] = bA; accB[r] = bB; }
  for (int c2 = 0; c2 < 32; ++c2) {
    float wa = w1[c2 * MLPD + tid];
    float wb2 = w1[c2 * MLPD + tid + 256];
    #pragma unroll
    for (int r = 0; r < 2; ++r) {
      float hv = hln[r][c2];
      accA[r] += hv * wa;
      accB[r] += hv * wb2;
    }
  }
  #pragma unroll
  for (int r = 0; r < 2; ++r) {
    a1s[r][tid]       = 0.5f * accA[r] * (1.0f + erff(accA[r] * 0.70710678118654752f));
    a1s[r][tid + 256] = 0.5f * accB[r] * (1.0f + erff(accB[r] * 0.70710678118654752f));
  }
  __syncthreads();
  const float* w2 = W2 + (size_t)layer * MLPD * CCH;
  float acc2[2] = {0.f, 0.f};
  #pragma unroll 4
  for (int mi = 0; mi < 64; ++mi) {
    int m = seg * 64 + mi;
    float w = w2[m * CCH + c];
    #pragma unroll
    for (int r = 0; r < 2; ++r) acc2[r] += a1s[r][m] * w;
  }
  __syncthreads();                    // part[] reuse
  #pragma unroll
  for (int r = 0; r < 2; ++r) part[r][seg][c] = acc2[r];
  __syncthreads();
  if (tid < 64) {
    int r = tid >> 5, cc = tid & 31;
    float s = b2[layer * CCH + cc] + res[r][cc];
    #pragma unroll
    for (int sg = 0; sg < 8; ++sg) s += part[r][sg][cc];
    fin[r][cc] = s;
    if (layer < 3) emb[(size_t)(row0 + r) * CCH + cc] = s;
  }
  __syncthreads();
  if (layer == 3) {
    if (tid < 64) {
      int r = tid >> 5, cc = tid & 31;
      int row = row0 + r;
      int b = row >> 9, ii = row & 511;
      int li = idx[b * NSEL + ii];
      out[((size_t)b * CCH + cc) * SEQL + li] = fin[r][cc];
    }
    return;
  }
  const int l1 = layer + 1;
  bool act = tid < 128;
  int hd = tid & 127;
  int hh = hd >> 5, d = hd & 31;
  #pragma unroll
  for (int r = 0; r < 2; ++r) {
    int row = row0 + r;
    int b = row >> 9, ii = row & 511;
    if (act) {
      float h[32];
      float mu = 0.f;
      #pragma unroll
      for (int c2 = 0; c2 < 32; ++c2) { h[c2] = fin[r][c2]; mu += h[c2]; }
      mu *= (1.0f / 32.0f);
      float var = 0.f;
      #pragma unroll
      for (int c2 = 0; c2 < 32; ++c2) { float dd = h[c2] - mu; var += dd * dd; }
      var *= (1.0f / 32.0f);
      float rstd = rsqrtf(var + 1e-5f);
      const float* g = ln1_g + l1 * CCH;
      const float* bb = ln1_b + l1 * CCH;
      #pragma unroll
      for (int c2 = 0; c2 < 32; ++c2) h[c2] = (h[c2] - mu) * rstd * g[c2] + bb[c2];
      const float* wq = Wq + (size_t)l1 * CCH * HDD + hd;
      const float* wk = Wk + (size_t)l1 * CCH * HDD + hd;
      const float* wv = Wv + (size_t)l1 * CCH * HDD + hd;
      float q = 0.f, kk = 0.f, vv = 0.f;
      #pragma unroll
      for (int c2 = 0; c2 < 32; ++c2) {
        q += h[c2] * wq[c2 * HDD];
        kk += h[c2] * wk[c2 * HDD];
        vv += h[c2] * wv[c2 * HDD];
      }
      q *= 0.17677669529663687f;
      qs[r][hd] = q;
      qc[(size_t)row * HDD + hd] = q + rcb[(l1 * NHEAD + hh) * DKD + d];
      size_t tpos = ((size_t)(b * 4 + hh) * 4 + (d >> 3)) * 4096 + (size_t)ii * 8 + (d & 7);
      kbT[tpos] = f2bf(kk);
      vT[tpos]  = f2bf(vv);
    }
  }
  __syncthreads();
  if (act && hd < 120) {
    int h2 = hd / 30, f = hd % 30;
    const float* rp = rpb + (l1 * NHEAD + h2) * DKD;
    const float* wr = Wrel + ((size_t)l1 * 30 + f) * HDD + h2 * DKD;
    #pragma unroll
    for (int r = 0; r < 2; ++r) {
      int row = row0 + r;
      const float* qsh = qs[r] + h2 * DKD;
      float acc = 0.f;
      #pragma unroll
      for (int dd = 0; dd < 32; ++dd) acc += (qsh[dd] + rp[dd]) * wr[dd];
      wb[((size_t)row * NHEAD + h2) * 32 + f] = acc;
    }
  }
}

extern "C" void kernel_launch(void* const* d_in, const int* in_sizes, int n_in,
                              void* d_out, int out_size, void* d_ws, size_t ws_size,
                              hipStream_t stream) {
  (void)in_sizes; (void)n_in; (void)ws_size; (void)out_size;
  const float* x_skip    = (const float*)d_in[0];
  const float* attention = (const float*)d_in[1];
  const float* ln1_g = (const float*)d_in[2];
  const float* ln1_b = (const float*)d_in[3];
  const float* Wq    = (const float*)d_in[4];
  const float* Wk    = (const float*)d_in[5];
  const float* Wv    = (const float*)d_in[6];
  const float* Wrel  = (const float*)d_in[7];
  const float* rcb   = (const float*)d_in[8];
  const float* rpb   = (const float*)d_in[9];
  const float* Wo    = (const float*)d_in[10];
  const float* bo    = (const float*)d_in[11];
  const float* ln2_g = (const float*)d_in[12];
  const float* ln2_b = (const float*)d_in[13];
  const float* W1    = (const float*)d_in[14];
  const float* b1    = (const float*)d_in[15];
  const float* W2    = (const float*)d_in[16];
  const float* b2    = (const float*)d_in[17];
  float* out = (float*)d_out;
  char* ws = (char*)d_ws;

  unsigned char* E = (unsigned char*)(ws + 0);        // 45000*16 = 720,000
  int*      idx   = (int*)(ws + 1441792);             // 4,096
  float*    emb   = (float*)(ws + 1445888);           // 131,072
  float*    qc    = (float*)(ws + 1576960);           // 524,288
  unsigned short* kbT = (unsigned short*)(ws + 2101248); // 262,144
  unsigned short* vT  = (unsigned short*)(ws + 2363392); // 262,144
  float*    wb    = (float*)(ws + 2625536);           // 524,288
  float*    ob    = (float*)(ws + 3149824);           // 524,288
  int*      hist  = (int*)(ws + 3674112);             // 1,048,576
  int*      cnt   = (int*)(ws + 4722688);             // 16
  unsigned long long* cand = (unsigned long long*)(ws + 4722720); // 65,536
  unsigned* chsel = (unsigned*)(ws + 4788256);        // 4,096

  hipMemsetAsync(ws + 3674112, 0, 1048576 + 32, stream);   // hist + cnt
  prep_kernel<<<ETB + 4 * TKB, 256, 0, stream>>>(attention, E, hist, out);
  topk_collect_kernel<<<4 * TKB, 256, 0, stream>>>(attention, hist, cand, cnt);
  topk_sort_kernel<<<4, 1024, 0, stream>>>(cand, cnt, chsel);
  topk_merge_kernel<<<2, 512, 0, stream>>>(chsel, idx);
  gqkv0_kernel<<<1024, 128, 0, stream>>>(x_skip, idx, ln1_g, ln1_b, Wq, Wk, Wv,
                                         Wrel, rcb, rpb, emb, qc, kbT, vT, wb);
  for (int l = 0; l < 4; ++l) {
    attn_kernel<<<512, 256, 0, stream>>>(qc, kbT, vT, wb, E, idx, ob);
    mlpqkv_kernel<<<512, 256, 0, stream>>>(ob, Wo, bo, ln2_g, ln2_b, W1, b1,
                                           W2, b2, ln1_g, ln1_b, Wq, Wk, Wv,
                                           Wrel, rcb, rpb, idx, emb, qc, kbT,
                                           vT, wb, out, l);
  }
}

// Round 13
// 333.341 us; speedup vs baseline: 4.4311x; 4.4311x over previous
//
#include <hip/hip_runtime.h>
#include <math.h>

#define SEQL   45000
#define NBAT   2
#define CCH    32
#define NSEL   512
#define NHEAD  4
#define DKD    32
#define HDD    128
#define MLPD   512
#define CDCAP  2048
#define TKB    32     // scan slices per (b,channel)
#define ETB    176    // etab blocks = ceil(45000/256)

// bf16 helpers: round-to-nearest-even pack, cheap unpack (<<16)
__device__ __forceinline__ unsigned short f2bf(float x) {
  unsigned u = __float_as_uint(x);
  u = (u + 0x7fffu + ((u >> 16) & 1u)) >> 16;
  return (unsigned short)u;
}
#define BFL(u) __uint_as_float((u) << 16)
#define BFH(u) __uint_as_float((u) & 0xffff0000u)
#define U8F(w, s) ((float)(((w) >> (s)) & 0xffu))

// ---------------- K0: etab build (u8) + high16 hist + d_out zero ------------
__global__ __launch_bounds__(256) void prep_kernel(const float* __restrict__ att,
                                                   unsigned char* __restrict__ E,
                                                   int* __restrict__ hist,
                                                   float* __restrict__ out) {
  {
    int nthr = gridDim.x * 256;
    int gt = blockIdx.x * 256 + threadIdx.x;
    float4 z4 = make_float4(0.f, 0.f, 0.f, 0.f);
    float4* o4 = (float4*)out;
    for (int i = gt; i < NBAT * CCH * SEQL / 4; i += nthr) o4[i] = z4;
  }
  if (blockIdx.x < ETB) {
    int a = blockIdx.x * 256 + threadIdx.x;
    if (a >= SEQL) return;
    float ad = (float)a;
    float outv[16];
    float log2S = log2f((float)SEQL);
    #pragma unroll
    for (int k = 0; k < 5; ++k) {
      float hl = exp2f(3.0f + (float)k * (log2S - 3.0f) * 0.25f);
      outv[k] = exp2f(-ad / hl);
    }
    const int cw[5] = {1, 3, 7, 15, 31};
    #pragma unroll
    for (int k = 0; k < 5; ++k) outv[5 + k] = (a < cw[k]) ? 1.0f : 0.0f;
    float pmax = 0.0f;
    float pk[5];
    #pragma unroll
    for (int k = 0; k < 5; ++k) {
      float mean = 9000.0f * (float)(k + 1);
      float sd = 4500.0f;
      float cc = (mean / sd) * (mean / sd);      // 4,16,36,64,100
      float rr = mean / (sd * sd);
      float logz = lgammaf(cc) - cc * logf(rr);
      float pp;
      if (a == 0) pp = 1e-8f;                    // xlogy -> -inf -> exp = 0
      else pp = expf((cc - 1.0f) * logf(ad) - rr * ad - logz) + 1e-8f;
      pk[k] = pp;
      float mstar = (cc - 1.0f) / rr;            // 6750..44550, interior mode
      float m0 = floorf(mstar), m1 = m0 + 1.0f;
      if (m1 > (float)(SEQL - 1)) m1 = (float)(SEQL - 1);
      float p0 = expf((cc - 1.0f) * logf(m0) - rr * m0 - logz) + 1e-8f;
      float p1 = expf((cc - 1.0f) * logf(m1) - rr * m1 - logz) + 1e-8f;
      pmax = fmaxf(pmax, fmaxf(p0, p1));
    }
    #pragma unroll
    for (int k = 0; k < 5; ++k) outv[10 + k] = pk[k] / pmax;
    outv[15] = 0.0f;
    unsigned by[16];
    #pragma unroll
    for (int k = 0; k < 15; ++k)
      by[k] = (unsigned)(fminf(fmaxf(outv[k], 0.f), 1.f) * 255.f + 0.5f);
    by[15] = 0u;
    uint4 o;
    o.x = by[0]  | (by[1]  << 8) | (by[2]  << 16) | (by[3]  << 24);
    o.y = by[4]  | (by[5]  << 8) | (by[6]  << 16) | (by[7]  << 24);
    o.z = by[8]  | (by[9]  << 8) | (by[10] << 16) | (by[11] << 24);
    o.w = by[12] | (by[13] << 8) | (by[14] << 16);
    *(uint4*)(E + (size_t)a * 16) = o;
  } else {
    int bid = blockIdx.x - ETB;
    int ch4 = bid / TKB;
    int blk = bid % TKB;
    int b = ch4 >> 1, ch = ch4 & 1;
    const float* row = att + ((size_t)b * 3 + 1 + ch) * SEQL;
    int* h = hist + (size_t)ch4 * 65536;
    int per = (SEQL + TKB - 1) / TKB;
    int lo = blk * per;
    int hi = lo + per; if (hi > SEQL) hi = SEQL;
    for (int i = lo + threadIdx.x; i < hi; i += 256)
      atomicAdd(&h[__float_as_uint(row[i]) >> 16], 1);  // vals>=0 -> monotone
  }
}

// ---------------- K1: collect w/ inline threshold ---------------------------
__global__ __launch_bounds__(256) void topk_collect_kernel(
    const float* __restrict__ att, const int* __restrict__ hist,
    unsigned long long* __restrict__ cand, int* __restrict__ cnt) {
  __shared__ int s_scan[256];
  __shared__ int s_aux[2];
  int tid = threadIdx.x;
  int ch4 = blockIdx.x / TKB;
  int blk = blockIdx.x % TKB;
  const int* h = hist + (size_t)ch4 * 65536;
  {
    int base = tid * 256;
    int sum = 0;
    for (int i = 0; i < 64; ++i) {
      int4 v = ((const int4*)(h + base))[i];
      sum += v.x + v.y + v.z + v.w;
    }
    s_scan[tid] = sum;
  }
  __syncthreads();
  for (int d = 1; d < 256; d <<= 1) {
    int v = s_scan[tid] + ((tid + d < 256) ? s_scan[tid + d] : 0);
    __syncthreads();
    s_scan[tid] = v;
    __syncthreads();
  }
  {
    int sufEx = (tid == 255) ? 0 : s_scan[tid + 1];
    if (s_scan[tid] >= 256 && sufEx < 256) { s_aux[0] = tid; s_aux[1] = 256 - sufEx; }
  }
  __syncthreads();
  int chunk = s_aux[0], want = s_aux[1];
  s_scan[tid] = h[chunk * 256 + tid];
  __syncthreads();
  for (int d = 1; d < 256; d <<= 1) {
    int v = s_scan[tid] + ((tid + d < 256) ? s_scan[tid + d] : 0);
    __syncthreads();
    s_scan[tid] = v;
    __syncthreads();
  }
  {
    int sufEx2 = (tid == 255) ? 0 : s_scan[tid + 1];
    if (s_scan[tid] >= want && sufEx2 < want) s_aux[0] = chunk * 256 + tid;
  }
  __syncthreads();
  unsigned T16 = (unsigned)s_aux[0];
  int b = ch4 >> 1, ch = ch4 & 1;
  const float* row = att + ((size_t)b * 3 + 1 + ch) * SEQL;
  int per = (SEQL + TKB - 1) / TKB;
  int lo = blk * per;
  int hi = lo + per; if (hi > SEQL) hi = SEQL;
  for (int i = lo + tid; i < hi; i += 256) {
    unsigned key = __float_as_uint(row[i]);
    if ((key >> 16) >= T16) {
      int p = atomicAdd(&cnt[ch4], 1);
      if (p < CDCAP)
        cand[(size_t)ch4 * CDCAP + p] =
            ((unsigned long long)key << 32) | (unsigned)(~(unsigned)i);
    }
  }
}

// ---------------- K2a: per-channel desc sort -> top-256 (4 parallel blocks) -
__global__ __launch_bounds__(1024) void topk_sort_kernel(
    const unsigned long long* __restrict__ cand, const int* __restrict__ cnt,
    unsigned* __restrict__ chsel) {
  __shared__ unsigned long long sc[CDCAP];
  int ch4 = blockIdx.x, t = threadIdx.x;
  int n = cnt[ch4]; if (n > CDCAP) n = CDCAP;   // >=256 by construction
  int P = 256;
  while (P < n) P <<= 1;                        // typical 512
  for (int i = t; i < P; i += 1024)
    sc[i] = (i < n) ? cand[(size_t)ch4 * CDCAP + i] : 0ull;  // 0 sorts last
  __syncthreads();
  for (int k = 2; k <= P; k <<= 1) {
    for (int j = k >> 1; j > 0; j >>= 1) {
      for (int i = t; i < P; i += 1024) {
        int ixj = i ^ j;
        if (ixj > i) {
          unsigned long long va = sc[i], vb2 = sc[ixj];
          bool up = ((i & k) == 0);
          if ((va < vb2) == up) { sc[i] = vb2; sc[ixj] = va; }
        }
      }
      __syncthreads();
    }
  }
  // desc u64 = value desc, tie -> larger ~i = smaller index first
  if (t < 256)
    chsel[(size_t)ch4 * 256 + t] = ~(unsigned)(sc[t] & 0xFFFFFFFFull);
}

// ---------------- K2b: merge acc+don, ascending sort of 512 -----------------
__global__ __launch_bounds__(512) void topk_merge_kernel(const unsigned* __restrict__ chsel,
                                                         int* __restrict__ idx) {
  __shared__ int m[512];
  int b = blockIdx.x, tid = threadIdx.x;
  m[tid] = (int)chsel[(size_t)b * 512 + tid];
  __syncthreads();
  for (int k = 2; k <= 512; k <<= 1) {
    for (int j = k >> 1; j > 0; j >>= 1) {
      int ixj = tid ^ j;
      if (ixj > tid) {
        int va = m[tid], vb2 = m[ixj];
        bool up = ((tid & k) == 0);
        if ((va > vb2) == up) { m[tid] = vb2; m[ixj] = va; }
      }
      __syncthreads();
    }
  }
  idx[b * 512 + tid] = m[tid];
}

// ---------------- K3: fused gather + LN1 + QKV layer 0 ----------------------
// kbT/vT layout (bf16): [((b*4+h)*4+dpack)*4096 + i*8 + (d&7)]
__global__ __launch_bounds__(128) void gqkv0_kernel(
    const float* __restrict__ x, const int* __restrict__ idx,
    const float* __restrict__ ln_g, const float* __restrict__ ln_b,
    const float* __restrict__ Wq, const float* __restrict__ Wk,
    const float* __restrict__ Wv, const float* __restrict__ Wrel,
    const float* __restrict__ rcb, const float* __restrict__ rpb,
    float* __restrict__ emb, float* __restrict__ qc,
    unsigned short* __restrict__ kbT, unsigned short* __restrict__ vT,
    float* __restrict__ wb) {
  __shared__ float qs[128];
  const int l = 0;
  int hd = threadIdx.x;        // 0..127
  int hh = hd >> 5, d = hd & 31;
  int row = blockIdx.x;        // b*512 + i
  int b = row >> 9, ii = row & 511;
  int li = idx[b * NSEL + ii];
  float h[32];
  float mu = 0.f;
  #pragma unroll
  for (int c = 0; c < 32; ++c) {
    h[c] = x[((size_t)b * CCH + c) * SEQL + li];
    mu += h[c];
  }
  if (hd < 32) emb[(size_t)row * CCH + hd] = h[hd];
  mu *= (1.0f / 32.0f);
  float var = 0.f;
  #pragma unroll
  for (int c = 0; c < 32; ++c) { float dd0 = h[c] - mu; var += dd0 * dd0; }
  var *= (1.0f / 32.0f);
  float rstd = rsqrtf(var + 1e-5f);
  const float* g = ln_g + l * CCH;
  const float* bb = ln_b + l * CCH;
  #pragma unroll
  for (int c = 0; c < 32; ++c) h[c] = (h[c] - mu) * rstd * g[c] + bb[c];
  const float* wq = Wq + (size_t)l * CCH * HDD + hd;
  const float* wk = Wk + (size_t)l * CCH * HDD + hd;
  const float* wv = Wv + (size_t)l * CCH * HDD + hd;
  float q = 0.f, kk = 0.f, vv = 0.f;
  #pragma unroll
  for (int c = 0; c < 32; ++c) {
    q += h[c] * wq[c * HDD];
    kk += h[c] * wk[c * HDD];
    vv += h[c] * wv[c * HDD];
  }
  q *= 0.17677669529663687f;   // DK^-0.5
  qs[hd] = q;
  qc[(size_t)row * HDD + hd] = q + rcb[(l * NHEAD + hh) * DKD + d];
  size_t tpos = ((size_t)(b * 4 + hh) * 4 + (d >> 3)) * 4096 + (size_t)ii * 8 + (d & 7);
  kbT[tpos] = f2bf(kk);
  vT[tpos]  = f2bf(vv);
  __syncthreads();
  if (hd < 120) {
    int h2 = hd / 30, f = hd % 30;
    const float* wr = Wrel + ((size_t)l * 30 + f) * HDD + h2 * DKD;
    const float* rp = rpb + (l * NHEAD + h2) * DKD;
    const float* qsh = qs + h2 * DKD;
    float acc = 0.f;
    #pragma unroll
    for (int dd = 0; dd < 32; ++dd) acc += (qsh[dd] + rp[dd]) * wr[dd];
    wb[((size_t)row * NHEAD + h2) * 32 + f] = acc;   // padded stride 32
  }
}

// ---------------- K4: attention (R11 version — reverted) --------------------
// R12's 66KB-LDS staging variant spilled ~3KB/thread to scratch (FETCH+WRITE
// ~190MB each, 10x regression). This global-kbT/vT version measured clean.
// 1024 blocks (b, h, 4 i-rows), 4 waves, 1 row/wave; u8-E single gather;
// reduced-shuffle PV epilogue.
__global__ __launch_bounds__(256, 4) void attn_kernel(
    const float* __restrict__ qc, const unsigned short* __restrict__ kbT,
    const unsigned short* __restrict__ vT, const float* __restrict__ wbuf,
    const unsigned char* __restrict__ E, const int* __restrict__ idx,
    float* __restrict__ ob) {
  __shared__ int idxl[512];
  int bid = blockIdx.x;
  int b = bid >> 9;
  int h = (bid >> 7) & 3;
  int i0 = (bid & 127) * 4;
  int tid = threadIdx.x;
  int wv = tid >> 6, ln = tid & 63;
  for (int i = tid; i < 512; i += 256) idxl[i] = idx[b * NSEL + i];
  __syncthreads();
  int i = i0 + wv;
  const float* qrow = qc + (size_t)(b * NSEL + i) * HDD + h * DKD;
  float q[32];
  #pragma unroll
  for (int d4 = 0; d4 < 8; ++d4) {
    float4 qv = *(const float4*)(qrow + d4 * 4);
    q[d4 * 4 + 0] = qv.x; q[d4 * 4 + 1] = qv.y;
    q[d4 * 4 + 2] = qv.z; q[d4 * 4 + 3] = qv.w;
  }
  const float* wrow = wbuf + ((size_t)(b * NSEL + i) * NHEAD + h) * 32;
  float w0[15], w1[15];
  #pragma unroll
  for (int f = 0; f < 15; ++f) {
    w0[f] = wrow[f] * (1.0f / 255.0f);        // u8 scale folded in
    w1[f] = wrow[15 + f] * (1.0f / 255.0f);
  }
  int ii = idxl[i];
  const uint4* kb4 = (const uint4*)kbT + (size_t)(b * 4 + h) * 4 * 512;
  const uint4* vb4 = (const uint4*)vT + (size_t)(b * 4 + h) * 4 * 512;
  float lg[8];
  #pragma unroll
  for (int u = 0; u < 8; ++u) {
    int j = u * 64 + ln;
    int dj = ii - idxl[j];
    float cacc = 0.f;
    #pragma unroll
    for (int dp = 0; dp < 4; ++dp) {
      uint4 kv = kb4[dp * 512 + j];
      cacc += q[dp * 8 + 0] * BFL(kv.x) + q[dp * 8 + 1] * BFH(kv.x)
            + q[dp * 8 + 2] * BFL(kv.y) + q[dp * 8 + 3] * BFH(kv.y)
            + q[dp * 8 + 4] * BFL(kv.z) + q[dp * 8 + 5] * BFH(kv.z)
            + q[dp * 8 + 6] * BFL(kv.w) + q[dp * 8 + 7] * BFH(kv.w);
    }
    int a = dj < 0 ? -dj : dj;
    uint4 e = *(const uint4*)(E + (size_t)a * 16);    // one 16B gather
    float r0 = U8F(e.x, 0)  * w0[0]  + U8F(e.x, 8)  * w0[1]
             + U8F(e.x, 16) * w0[2]  + U8F(e.x, 24) * w0[3]
             + U8F(e.y, 0)  * w0[4]  + U8F(e.y, 8)  * w0[5]
             + U8F(e.y, 16) * w0[6]  + U8F(e.y, 24) * w0[7]
             + U8F(e.z, 0)  * w0[8]  + U8F(e.z, 8)  * w0[9]
             + U8F(e.z, 16) * w0[10] + U8F(e.z, 24) * w0[11]
             + U8F(e.w, 0)  * w0[12] + U8F(e.w, 8)  * w0[13]
             + U8F(e.w, 16) * w0[14];
    float r1 = U8F(e.x, 0)  * w1[0]  + U8F(e.x, 8)  * w1[1]
             + U8F(e.x, 16) * w1[2]  + U8F(e.x, 24) * w1[3]
             + U8F(e.y, 0)  * w1[4]  + U8F(e.y, 8)  * w1[5]
             + U8F(e.y, 16) * w1[6]  + U8F(e.y, 24) * w1[7]
             + U8F(e.z, 0)  * w1[8]  + U8F(e.z, 8)  * w1[9]
             + U8F(e.z, 16) * w1[10] + U8F(e.z, 24) * w1[11]
             + U8F(e.w, 0)  * w1[12] + U8F(e.w, 8)  * w1[13]
             + U8F(e.w, 16) * w1[14];
    float sgn = dj > 0 ? 1.f : (dj < 0 ? -1.f : 0.f);
    lg[u] = cacc + r0 + sgn * r1;
  }
  // full-row softmax across the wave (512 logits, 8/lane), in registers
  float m = lg[0];
  #pragma unroll
  for (int u = 1; u < 8; ++u) m = fmaxf(m, lg[u]);
  #pragma unroll
  for (int s = 1; s < 64; s <<= 1) m = fmaxf(m, __shfl_xor(m, s));
  float ssum = 0.f;
  #pragma unroll
  for (int u = 0; u < 8; ++u) { lg[u] = __expf(lg[u] - m); ssum += lg[u]; }
  #pragma unroll
  for (int s = 1; s < 64; s <<= 1) ssum += __shfl_xor(ssum, s);
  float invs = 1.0f / ssum;
  // PV: p in registers, v coalesced; reduced-shuffle epilogue
  float* obrow = ob + (size_t)(b * NSEL + i) * HDD + h * DKD;
  #pragma unroll
  for (int dp = 0; dp < 4; ++dp) {
    float acc[8] = {0.f, 0.f, 0.f, 0.f, 0.f, 0.f, 0.f, 0.f};
    #pragma unroll
    for (int u = 0; u < 8; ++u) {
      uint4 vv = vb4[dp * 512 + u * 64 + ln];
      float p = lg[u];
      acc[0] += p * BFL(vv.x); acc[1] += p * BFH(vv.x);
      acc[2] += p * BFL(vv.y); acc[3] += p * BFH(vv.y);
      acc[4] += p * BFL(vv.z); acc[5] += p * BFH(vv.z);
      acc[6] += p * BFL(vv.w); acc[7] += p * BFH(vv.w);
    }
    // octet-reduce all 8 accs (stages 1,2,4)
    #pragma unroll
    for (int s = 1; s < 8; s <<= 1) {
      #pragma unroll
      for (int t = 0; t < 8; ++t) acc[t] += __shfl_xor(acc[t], s);
    }
    // lane picks its d = ln&7, then cross-octet reduce (stages 8,16,32)
    int sel = ln & 7;
    float y = acc[0];
    #pragma unroll
    for (int t = 1; t < 8; ++t) y = (sel == t) ? acc[t] : y;
    #pragma unroll
    for (int s = 8; s < 64; s <<= 1) y += __shfl_xor(y, s);
    if (ln < 8) obrow[dp * 8 + ln] = y * invs;
  }
}

// ---------------- K5: fused proj+res+LN2+MLP+res (2 rows) + qkv(l+1)/scatter
__global__ __launch_bounds__(256) void mlpqkv_kernel(
    const float* __restrict__ ob, const float* __restrict__ Wo,
    const float* __restrict__ bo,
    const float* __restrict__ ln2_g, const float* __restrict__ ln2_b,
    const float* __restrict__ W1, const float* __restrict__ b1,
    const float* __restrict__ W2, const float* __restrict__ b2,
    const float* __restrict__ ln1_g, const float* __restrict__ ln1_b,
    const float* __restrict__ Wq, const float* __restrict__ Wk,
    const float* __restrict__ Wv, const float* __restrict__ Wrel,
    const float* __restrict__ rcb, const float* __restrict__ rpb,
    const int* __restrict__ idx, float* __restrict__ emb,
    float* __restrict__ qc, unsigned short* __restrict__ kbT,
    unsigned short* __restrict__ vT, float* __restrict__ wb,
    float* __restrict__ out, int layer) {
  __shared__ float part[2][8][32];
  __shared__ float res[2][32];
  __shared__ float hln[2][32];
  __shared__ float fin[2][32];
  __shared__ float a1s[2][MLPD];
  __shared__ float qs[2][128];
  int row0 = blockIdx.x * 2;
  int tid = threadIdx.x;
  int c = tid & 31, seg = tid >> 5;
  const float* wo = Wo + (size_t)layer * HDD * CCH + c;
  float pacc[2] = {0.f, 0.f};
  #pragma unroll
  for (int k = 0; k < 16; ++k) {
    int kk = seg * 16 + k;
    float w = wo[kk * CCH];
    #pragma unroll
    for (int r = 0; r < 2; ++r)
      pacc[r] += ob[(size_t)(row0 + r) * HDD + kk] * w;
  }
  #pragma unroll
  for (int r = 0; r < 2; ++r) part[r][seg][c] = pacc[r];
  __syncthreads();
  if (tid < 64) {
    int r = tid >> 5, cc = tid & 31;
    float s = bo[layer * CCH + cc] + emb[(size_t)(row0 + r) * CCH + cc];
    #pragma unroll
    for (int sg = 0; sg < 8; ++sg) s += part[r][sg][cc];
    res[r][cc] = s;
  }
  __syncthreads();
  if (tid < 64) {
    int r = tid >> 5, cc = tid & 31;
    float mu = 0.f, s2 = 0.f;
    #pragma unroll
    for (int c2 = 0; c2 < 32; ++c2) { float v = res[r][c2]; mu += v; s2 += v * v; }
    mu *= (1.0f / 32.0f);
    float var = s2 * (1.0f / 32.0f) - mu * mu;
    float rstd = rsqrtf(var + 1e-5f);
    hln[r][cc] = (res[r][cc] - mu) * rstd * ln2_g[layer * CCH + cc] + ln2_b[layer * CCH + cc];
  }
  __syncthreads();
  const float* w1 = W1 + (size_t)layer * CCH * MLPD;
  float accA[2], accB[2];
  float bA = b1[layer * MLPD + tid], bB = b1[layer * MLPD + tid + 256];
  #pragma unroll
  for (int r = 0; r < 2; ++r) { accA[r] = bA; accB[r] = bB; }
  for (int c2 = 0; c2 < 32; ++c2) {
    float wa = w1[c2 * MLPD + tid];
    float wb2 = w1[c2 * MLPD + tid + 256];
    #pragma unroll
    for (int r = 0; r < 2; ++r) {
      float hv = hln[r][c2];
      accA[r] += hv * wa;
      accB[r] += hv * wb2;
    }
  }
  #pragma unroll
  for (int r = 0; r < 2; ++r) {
    a1s[r][tid]       = 0.5f * accA[r] * (1.0f + erff(accA[r] * 0.70710678118654752f));
    a1s[r][tid + 256] = 0.5f * accB[r] * (1.0f + erff(accB[r] * 0.70710678118654752f));
  }
  __syncthreads();
  const float* w2 = W2 + (size_t)layer * MLPD * CCH;
  float acc2[2] = {0.f, 0.f};
  #pragma unroll 4
  for (int mi = 0; mi < 64; ++mi) {
    int m = seg * 64 + mi;
    float w = w2[m * CCH + c];
    #pragma unroll
    for (int r = 0; r < 2; ++r) acc2[r] += a1s[r][m] * w;
  }
  __syncthreads();                    // part[] reuse
  #pragma unroll
  for (int r = 0; r < 2; ++r) part[r][seg][c] = acc2[r];
  __syncthreads();
  if (tid < 64) {
    int r = tid >> 5, cc = tid & 31;
    float s = b2[layer * CCH + cc] + res[r][cc];
    #pragma unroll
    for (int sg = 0; sg < 8; ++sg) s += part[r][sg][cc];
    fin[r][cc] = s;
    if (layer < 3) emb[(size_t)(row0 + r) * CCH + cc] = s;
  }
  __syncthreads();
  if (layer == 3) {
    if (tid < 64) {
      int r = tid >> 5, cc = tid & 31;
      int row = row0 + r;
      int b = row >> 9, ii = row & 511;
      int li = idx[b * NSEL + ii];
      out[((size_t)b * CCH + cc) * SEQL + li] = fin[r][cc];
    }
    return;
  }
  const int l1 = layer + 1;
  bool act = tid < 128;
  int hd = tid & 127;
  int hh = hd >> 5, d = hd & 31;
  #pragma unroll
  for (int r = 0; r < 2; ++r) {
    int row = row0 + r;
    int b = row >> 9, ii = row & 511;
    if (act) {
      float h[32];
      float mu = 0.f;
      #pragma unroll
      for (int c2 = 0; c2 < 32; ++c2) { h[c2] = fin[r][c2]; mu += h[c2]; }
      mu *= (1.0f / 32.0f);
      float var = 0.f;
      #pragma unroll
      for (int c2 = 0; c2 < 32; ++c2) { float dd = h[c2] - mu; var += dd * dd; }
      var *= (1.0f / 32.0f);
      float rstd = rsqrtf(var + 1e-5f);
      const float* g = ln1_g + l1 * CCH;
      const float* bb = ln1_b + l1 * CCH;
      #pragma unroll
      for (int c2 = 0; c2 < 32; ++c2) h[c2] = (h[c2] - mu) * rstd * g[c2] + bb[c2];
      const float* wq = Wq + (size_t)l1 * CCH * HDD + hd;
      const float* wk = Wk + (size_t)l1 * CCH * HDD + hd;
      const float* wv = Wv + (size_t)l1 * CCH * HDD + hd;
      float q = 0.f, kk = 0.f, vv = 0.f;
      #pragma unroll
      for (int c2 = 0; c2 < 32; ++c2) {
        q += h[c2] * wq[c2 * HDD];
        kk += h[c2] * wk[c2 * HDD];
        vv += h[c2] * wv[c2 * HDD];
      }
      q *= 0.17677669529663687f;
      qs[r][hd] = q;
      qc[(size_t)row * HDD + hd] = q + rcb[(l1 * NHEAD + hh) * DKD + d];
      size_t tpos = ((size_t)(b * 4 + hh) * 4 + (d >> 3)) * 4096 + (size_t)ii * 8 + (d & 7);
      kbT[tpos] = f2bf(kk);
      vT[tpos]  = f2bf(vv);
    }
  }
  __syncthreads();
  if (act && hd < 120) {
    int h2 = hd / 30, f = hd % 30;
    const float* rp = rpb + (l1 * NHEAD + h2) * DKD;
    const float* wr = Wrel + ((size_t)l1 * 30 + f) * HDD + h2 * DKD;
    #pragma unroll
    for (int r = 0; r < 2; ++r) {
      int row = row0 + r;
      const float* qsh = qs[r] + h2 * DKD;
      float acc = 0.f;
      #pragma unroll
      for (int dd = 0; dd < 32; ++dd) acc += (qsh[dd] + rp[dd]) * wr[dd];
      wb[((size_t)row * NHEAD + h2) * 32 + f] = acc;
    }
  }
}

extern "C" void kernel_launch(void* const* d_in, const int* in_sizes, int n_in,
                              void* d_out, int out_size, void* d_ws, size_t ws_size,
                              hipStream_t stream) {
  (void)in_sizes; (void)n_in; (void)ws_size; (void)out_size;
  const float* x_skip    = (const float*)d_in[0];
  const float* attention = (const float*)d_in[1];
  const float* ln1_g = (const float*)d_in[2];
  const float* ln1_b = (const float*)d_in[3];
  const float* Wq    = (const float*)d_in[4];
  const float* Wk    = (const float*)d_in[5];
  const float* Wv    = (const float*)d_in[6];
  const float* Wrel  = (const float*)d_in[7];
  const float* rcb   = (const float*)d_in[8];
  const float* rpb   = (const float*)d_in[9];
  const float* Wo    = (const float*)d_in[10];
  const float* bo    = (const float*)d_in[11];
  const float* ln2_g = (const float*)d_in[12];
  const float* ln2_b = (const float*)d_in[13];
  const float* W1    = (const float*)d_in[14];
  const float* b1    = (const float*)d_in[15];
  const float* W2    = (const float*)d_in[16];
  const float* b2    = (const float*)d_in[17];
  float* out = (float*)d_out;
  char* ws = (char*)d_ws;

  unsigned char* E = (unsigned char*)(ws + 0);        // 45000*16 = 720,000
  int*      idx   = (int*)(ws + 1441792);             // 4,096
  float*    emb   = (float*)(ws + 1445888);           // 131,072
  float*    qc    = (float*)(ws + 1576960);           // 524,288
  unsigned short* kbT = (unsigned short*)(ws + 2101248); // 262,144
  unsigned short* vT  = (unsigned short*)(ws + 2363392); // 262,144
  float*    wb    = (float*)(ws + 2625536);           // 524,288
  float*    ob    = (float*)(ws + 3149824);           // 524,288
  int*      hist  = (int*)(ws + 3674112);             // 1,048,576
  int*      cnt   = (int*)(ws + 4722688);             // 16
  unsigned long long* cand = (unsigned long long*)(ws + 4722720); // 65,536
  unsigned* chsel = (unsigned*)(ws + 4788256);        // 4,096

  hipMemsetAsync(ws + 3674112, 0, 1048576 + 32, stream);   // hist + cnt
  prep_kernel<<<ETB + 4 * TKB, 256, 0, stream>>>(attention, E, hist, out);
  topk_collect_kernel<<<4 * TKB, 256, 0, stream>>>(attention, hist, cand, cnt);
  topk_sort_kernel<<<4, 1024, 0, stream>>>(cand, cnt, chsel);
  topk_merge_kernel<<<2, 512, 0, stream>>>(chsel, idx);
  gqkv0_kernel<<<1024, 128, 0, stream>>>(x_skip, idx, ln1_g, ln1_b, Wq, Wk, Wv,
                                         Wrel, rcb, rpb, emb, qc, kbT, vT, wb);
  for (int l = 0; l < 4; ++l) {
    attn_kernel<<<1024, 256, 0, stream>>>(qc, kbT, vT, wb, E, idx, ob);
    mlpqkv_kernel<<<512, 256, 0, stream>>>(ob, Wo, bo, ln2_g, ln2_b, W1, b1,
                                           W2, b2, ln1_g, ln1_b, Wq, Wk, Wv,
                                           Wrel, rcb, rpb, idx, emb, qc, kbT,
                                           vT, wb, out, l);
  }
}

// Round 14
// 323.055 us; speedup vs baseline: 4.5722x; 1.0318x over previous
//
#include <hip/hip_runtime.h>
#include <math.h>

#define SEQL   45000
#define NBAT   2
#define CCH    32
#define NSEL   512
#define NHEAD  4
#define DKD    32
#define HDD    128
#define MLPD   512
#define CDCAP  2048
#define TKB    32     // scan slices per (b,channel)
#define ETB    176    // etab blocks = ceil(45000/256)

// bf16 helpers: round-to-nearest-even pack, cheap unpack (<<16)
__device__ __forceinline__ unsigned short f2bf(float x) {
  unsigned u = __float_as_uint(x);
  u = (u + 0x7fffu + ((u >> 16) & 1u)) >> 16;
  return (unsigned short)u;
}
#define BFL(u) __uint_as_float((u) << 16)
#define BFH(u) __uint_as_float((u) & 0xffff0000u)
#define U8F(w, s) ((float)(((w) >> (s)) & 0xffu))

// ---------------- K0: etab build (u8) + high16 hist + d_out zero ------------
__global__ __launch_bounds__(256) void prep_kernel(const float* __restrict__ att,
                                                   unsigned char* __restrict__ E,
                                                   int* __restrict__ hist,
                                                   float* __restrict__ out) {
  {
    int nthr = gridDim.x * 256;
    int gt = blockIdx.x * 256 + threadIdx.x;
    float4 z4 = make_float4(0.f, 0.f, 0.f, 0.f);
    float4* o4 = (float4*)out;
    for (int i = gt; i < NBAT * CCH * SEQL / 4; i += nthr) o4[i] = z4;
  }
  if (blockIdx.x < ETB) {
    int a = blockIdx.x * 256 + threadIdx.x;
    if (a >= SEQL) return;
    float ad = (float)a;
    float outv[16];
    float log2S = log2f((float)SEQL);
    #pragma unroll
    for (int k = 0; k < 5; ++k) {
      float hl = exp2f(3.0f + (float)k * (log2S - 3.0f) * 0.25f);
      outv[k] = exp2f(-ad / hl);
    }
    const int cw[5] = {1, 3, 7, 15, 31};
    #pragma unroll
    for (int k = 0; k < 5; ++k) outv[5 + k] = (a < cw[k]) ? 1.0f : 0.0f;
    float pmax = 0.0f;
    float pk[5];
    #pragma unroll
    for (int k = 0; k < 5; ++k) {
      float mean = 9000.0f * (float)(k + 1);
      float sd = 4500.0f;
      float cc = (mean / sd) * (mean / sd);      // 4,16,36,64,100
      float rr = mean / (sd * sd);
      float logz = lgammaf(cc) - cc * logf(rr);
      float pp;
      if (a == 0) pp = 1e-8f;                    // xlogy -> -inf -> exp = 0
      else pp = expf((cc - 1.0f) * logf(ad) - rr * ad - logz) + 1e-8f;
      pk[k] = pp;
      float mstar = (cc - 1.0f) / rr;            // 6750..44550, interior mode
      float m0 = floorf(mstar), m1 = m0 + 1.0f;
      if (m1 > (float)(SEQL - 1)) m1 = (float)(SEQL - 1);
      float p0 = expf((cc - 1.0f) * logf(m0) - rr * m0 - logz) + 1e-8f;
      float p1 = expf((cc - 1.0f) * logf(m1) - rr * m1 - logz) + 1e-8f;
      pmax = fmaxf(pmax, fmaxf(p0, p1));
    }
    #pragma unroll
    for (int k = 0; k < 5; ++k) outv[10 + k] = pk[k] / pmax;
    outv[15] = 0.0f;
    unsigned by[16];
    #pragma unroll
    for (int k = 0; k < 15; ++k)
      by[k] = (unsigned)(fminf(fmaxf(outv[k], 0.f), 1.f) * 255.f + 0.5f);
    by[15] = 0u;
    uint4 o;
    o.x = by[0]  | (by[1]  << 8) | (by[2]  << 16) | (by[3]  << 24);
    o.y = by[4]  | (by[5]  << 8) | (by[6]  << 16) | (by[7]  << 24);
    o.z = by[8]  | (by[9]  << 8) | (by[10] << 16) | (by[11] << 24);
    o.w = by[12] | (by[13] << 8) | (by[14] << 16);
    *(uint4*)(E + (size_t)a * 16) = o;
  } else {
    int bid = blockIdx.x - ETB;
    int ch4 = bid / TKB;
    int blk = bid % TKB;
    int b = ch4 >> 1, ch = ch4 & 1;
    const float* row = att + ((size_t)b * 3 + 1 + ch) * SEQL;
    int* h = hist + (size_t)ch4 * 65536;
    int per = (SEQL + TKB - 1) / TKB;
    int lo = blk * per;
    int hi = lo + per; if (hi > SEQL) hi = SEQL;
    for (int i = lo + threadIdx.x; i < hi; i += 256)
      atomicAdd(&h[__float_as_uint(row[i]) >> 16], 1);  // vals>=0 -> monotone
  }
}

// ---------------- K1: collect w/ inline threshold ---------------------------
__global__ __launch_bounds__(256) void topk_collect_kernel(
    const float* __restrict__ att, const int* __restrict__ hist,
    unsigned long long* __restrict__ cand, int* __restrict__ cnt) {
  __shared__ int s_scan[256];
  __shared__ int s_aux[2];
  int tid = threadIdx.x;
  int ch4 = blockIdx.x / TKB;
  int blk = blockIdx.x % TKB;
  const int* h = hist + (size_t)ch4 * 65536;
  {
    int base = tid * 256;
    int sum = 0;
    for (int i = 0; i < 64; ++i) {
      int4 v = ((const int4*)(h + base))[i];
      sum += v.x + v.y + v.z + v.w;
    }
    s_scan[tid] = sum;
  }
  __syncthreads();
  for (int d = 1; d < 256; d <<= 1) {
    int v = s_scan[tid] + ((tid + d < 256) ? s_scan[tid + d] : 0);
    __syncthreads();
    s_scan[tid] = v;
    __syncthreads();
  }
  {
    int sufEx = (tid == 255) ? 0 : s_scan[tid + 1];
    if (s_scan[tid] >= 256 && sufEx < 256) { s_aux[0] = tid; s_aux[1] = 256 - sufEx; }
  }
  __syncthreads();
  int chunk = s_aux[0], want = s_aux[1];
  s_scan[tid] = h[chunk * 256 + tid];
  __syncthreads();
  for (int d = 1; d < 256; d <<= 1) {
    int v = s_scan[tid] + ((tid + d < 256) ? s_scan[tid + d] : 0);
    __syncthreads();
    s_scan[tid] = v;
    __syncthreads();
  }
  {
    int sufEx2 = (tid == 255) ? 0 : s_scan[tid + 1];
    if (s_scan[tid] >= want && sufEx2 < want) s_aux[0] = chunk * 256 + tid;
  }
  __syncthreads();
  unsigned T16 = (unsigned)s_aux[0];
  int b = ch4 >> 1, ch = ch4 & 1;
  const float* row = att + ((size_t)b * 3 + 1 + ch) * SEQL;
  int per = (SEQL + TKB - 1) / TKB;
  int lo = blk * per;
  int hi = lo + per; if (hi > SEQL) hi = SEQL;
  for (int i = lo + tid; i < hi; i += 256) {
    unsigned key = __float_as_uint(row[i]);
    if ((key >> 16) >= T16) {
      int p = atomicAdd(&cnt[ch4], 1);
      if (p < CDCAP)
        cand[(size_t)ch4 * CDCAP + p] =
            ((unsigned long long)key << 32) | (unsigned)(~(unsigned)i);
    }
  }
}

// ---------------- K2a: per-channel desc sort -> top-256 (4 parallel blocks) -
__global__ __launch_bounds__(1024) void topk_sort_kernel(
    const unsigned long long* __restrict__ cand, const int* __restrict__ cnt,
    unsigned* __restrict__ chsel) {
  __shared__ unsigned long long sc[CDCAP];
  int ch4 = blockIdx.x, t = threadIdx.x;
  int n = cnt[ch4]; if (n > CDCAP) n = CDCAP;   // >=256 by construction
  int P = 256;
  while (P < n) P <<= 1;                        // typical 512
  for (int i = t; i < P; i += 1024)
    sc[i] = (i < n) ? cand[(size_t)ch4 * CDCAP + i] : 0ull;  // 0 sorts last
  __syncthreads();
  for (int k = 2; k <= P; k <<= 1) {
    for (int j = k >> 1; j > 0; j >>= 1) {
      for (int i = t; i < P; i += 1024) {
        int ixj = i ^ j;
        if (ixj > i) {
          unsigned long long va = sc[i], vb2 = sc[ixj];
          bool up = ((i & k) == 0);
          if ((va < vb2) == up) { sc[i] = vb2; sc[ixj] = va; }
        }
      }
      __syncthreads();
    }
  }
  // desc u64 = value desc, tie -> larger ~i = smaller index first
  if (t < 256)
    chsel[(size_t)ch4 * 256 + t] = ~(unsigned)(sc[t] & 0xFFFFFFFFull);
}

// ---------------- K2b: merge acc+don, ascending sort of 512 -----------------
__global__ __launch_bounds__(512) void topk_merge_kernel(const unsigned* __restrict__ chsel,
                                                         int* __restrict__ idx) {
  __shared__ int m[512];
  int b = blockIdx.x, tid = threadIdx.x;
  m[tid] = (int)chsel[(size_t)b * 512 + tid];
  __syncthreads();
  for (int k = 2; k <= 512; k <<= 1) {
    for (int j = k >> 1; j > 0; j >>= 1) {
      int ixj = tid ^ j;
      if (ixj > tid) {
        int va = m[tid], vb2 = m[ixj];
        bool up = ((tid & k) == 0);
        if ((va > vb2) == up) { m[tid] = vb2; m[ixj] = va; }
      }
      __syncthreads();
    }
  }
  idx[b * 512 + tid] = m[tid];
}

// ---------------- K3: fused gather + LN1 + QKV layer 0 ----------------------
// kbT/vT layout (bf16): [((b*4+h)*4+dpack)*4096 + i*8 + (d&7)]
__global__ __launch_bounds__(128) void gqkv0_kernel(
    const float* __restrict__ x, const int* __restrict__ idx,
    const float* __restrict__ ln_g, const float* __restrict__ ln_b,
    const float* __restrict__ Wq, const float* __restrict__ Wk,
    const float* __restrict__ Wv, const float* __restrict__ Wrel,
    const float* __restrict__ rcb, const float* __restrict__ rpb,
    float* __restrict__ emb, float* __restrict__ qc,
    unsigned short* __restrict__ kbT, unsigned short* __restrict__ vT,
    float* __restrict__ wb) {
  __shared__ float qs[128];
  const int l = 0;
  int hd = threadIdx.x;        // 0..127
  int hh = hd >> 5, d = hd & 31;
  int row = blockIdx.x;        // b*512 + i
  int b = row >> 9, ii = row & 511;
  int li = idx[b * NSEL + ii];
  float h[32];
  float mu = 0.f;
  #pragma unroll
  for (int c = 0; c < 32; ++c) {
    h[c] = x[((size_t)b * CCH + c) * SEQL + li];
    mu += h[c];
  }
  if (hd < 32) emb[(size_t)row * CCH + hd] = h[hd];
  mu *= (1.0f / 32.0f);
  float var = 0.f;
  #pragma unroll
  for (int c = 0; c < 32; ++c) { float dd0 = h[c] - mu; var += dd0 * dd0; }
  var *= (1.0f / 32.0f);
  float rstd = rsqrtf(var + 1e-5f);
  const float* g = ln_g + l * CCH;
  const float* bb = ln_b + l * CCH;
  #pragma unroll
  for (int c = 0; c < 32; ++c) h[c] = (h[c] - mu) * rstd * g[c] + bb[c];
  const float* wq = Wq + (size_t)l * CCH * HDD + hd;
  const float* wk = Wk + (size_t)l * CCH * HDD + hd;
  const float* wv = Wv + (size_t)l * CCH * HDD + hd;
  float q = 0.f, kk = 0.f, vv = 0.f;
  #pragma unroll
  for (int c = 0; c < 32; ++c) {
    q += h[c] * wq[c * HDD];
    kk += h[c] * wk[c * HDD];
    vv += h[c] * wv[c * HDD];
  }
  q *= 0.17677669529663687f;   // DK^-0.5
  qs[hd] = q;
  qc[(size_t)row * HDD + hd] = q + rcb[(l * NHEAD + hh) * DKD + d];
  size_t tpos = ((size_t)(b * 4 + hh) * 4 + (d >> 3)) * 4096 + (size_t)ii * 8 + (d & 7);
  kbT[tpos] = f2bf(kk);
  vT[tpos]  = f2bf(vv);
  __syncthreads();
  if (hd < 120) {
    int h2 = hd / 30, f = hd % 30;
    const float* wr = Wrel + ((size_t)l * 30 + f) * HDD + h2 * DKD;
    const float* rp = rpb + (l * NHEAD + h2) * DKD;
    const float* qsh = qs + h2 * DKD;
    float acc = 0.f;
    #pragma unroll
    for (int dd = 0; dd < 32; ++dd) acc += (qsh[dd] + rp[dd]) * wr[dd];
    wb[((size_t)row * NHEAD + h2) * 32 + f] = acc;   // padded stride 32
  }
}

// ---------------- K4: attention (R11/R13 version — proven clean) ------------
// 1024 blocks (b, h, 4 i-rows), 4 waves, 1 row/wave; u8-E single gather;
// reduced-shuffle PV epilogue. (R12 LDS-staging variant spilled — retired.)
__global__ __launch_bounds__(256, 4) void attn_kernel(
    const float* __restrict__ qc, const unsigned short* __restrict__ kbT,
    const unsigned short* __restrict__ vT, const float* __restrict__ wbuf,
    const unsigned char* __restrict__ E, const int* __restrict__ idx,
    float* __restrict__ ob) {
  __shared__ int idxl[512];
  int bid = blockIdx.x;
  int b = bid >> 9;
  int h = (bid >> 7) & 3;
  int i0 = (bid & 127) * 4;
  int tid = threadIdx.x;
  int wv = tid >> 6, ln = tid & 63;
  for (int i = tid; i < 512; i += 256) idxl[i] = idx[b * NSEL + i];
  __syncthreads();
  int i = i0 + wv;
  const float* qrow = qc + (size_t)(b * NSEL + i) * HDD + h * DKD;
  float q[32];
  #pragma unroll
  for (int d4 = 0; d4 < 8; ++d4) {
    float4 qv = *(const float4*)(qrow + d4 * 4);
    q[d4 * 4 + 0] = qv.x; q[d4 * 4 + 1] = qv.y;
    q[d4 * 4 + 2] = qv.z; q[d4 * 4 + 3] = qv.w;
  }
  const float* wrow = wbuf + ((size_t)(b * NSEL + i) * NHEAD + h) * 32;
  float w0[15], w1[15];
  #pragma unroll
  for (int f = 0; f < 15; ++f) {
    w0[f] = wrow[f] * (1.0f / 255.0f);        // u8 scale folded in
    w1[f] = wrow[15 + f] * (1.0f / 255.0f);
  }
  int ii = idxl[i];
  const uint4* kb4 = (const uint4*)kbT + (size_t)(b * 4 + h) * 4 * 512;
  const uint4* vb4 = (const uint4*)vT + (size_t)(b * 4 + h) * 4 * 512;
  float lg[8];
  #pragma unroll
  for (int u = 0; u < 8; ++u) {
    int j = u * 64 + ln;
    int dj = ii - idxl[j];
    float cacc = 0.f;
    #pragma unroll
    for (int dp = 0; dp < 4; ++dp) {
      uint4 kv = kb4[dp * 512 + j];
      cacc += q[dp * 8 + 0] * BFL(kv.x) + q[dp * 8 + 1] * BFH(kv.x)
            + q[dp * 8 + 2] * BFL(kv.y) + q[dp * 8 + 3] * BFH(kv.y)
            + q[dp * 8 + 4] * BFL(kv.z) + q[dp * 8 + 5] * BFH(kv.z)
            + q[dp * 8 + 6] * BFL(kv.w) + q[dp * 8 + 7] * BFH(kv.w);
    }
    int a = dj < 0 ? -dj : dj;
    uint4 e = *(const uint4*)(E + (size_t)a * 16);    // one 16B gather
    float r0 = U8F(e.x, 0)  * w0[0]  + U8F(e.x, 8)  * w0[1]
             + U8F(e.x, 16) * w0[2]  + U8F(e.x, 24) * w0[3]
             + U8F(e.y, 0)  * w0[4]  + U8F(e.y, 8)  * w0[5]
             + U8F(e.y, 16) * w0[6]  + U8F(e.y, 24) * w0[7]
             + U8F(e.z, 0)  * w0[8]  + U8F(e.z, 8)  * w0[9]
             + U8F(e.z, 16) * w0[10] + U8F(e.z, 24) * w0[11]
             + U8F(e.w, 0)  * w0[12] + U8F(e.w, 8)  * w0[13]
             + U8F(e.w, 16) * w0[14];
    float r1 = U8F(e.x, 0)  * w1[0]  + U8F(e.x, 8)  * w1[1]
             + U8F(e.x, 16) * w1[2]  + U8F(e.x, 24) * w1[3]
             + U8F(e.y, 0)  * w1[4]  + U8F(e.y, 8)  * w1[5]
             + U8F(e.y, 16) * w1[6]  + U8F(e.y, 24) * w1[7]
             + U8F(e.z, 0)  * w1[8]  + U8F(e.z, 8)  * w1[9]
             + U8F(e.z, 16) * w1[10] + U8F(e.z, 24) * w1[11]
             + U8F(e.w, 0)  * w1[12] + U8F(e.w, 8)  * w1[13]
             + U8F(e.w, 16) * w1[14];
    float sgn = dj > 0 ? 1.f : (dj < 0 ? -1.f : 0.f);
    lg[u] = cacc + r0 + sgn * r1;
  }
  // full-row softmax across the wave (512 logits, 8/lane), in registers
  float m = lg[0];
  #pragma unroll
  for (int u = 1; u < 8; ++u) m = fmaxf(m, lg[u]);
  #pragma unroll
  for (int s = 1; s < 64; s <<= 1) m = fmaxf(m, __shfl_xor(m, s));
  float ssum = 0.f;
  #pragma unroll
  for (int u = 0; u < 8; ++u) { lg[u] = __expf(lg[u] - m); ssum += lg[u]; }
  #pragma unroll
  for (int s = 1; s < 64; s <<= 1) ssum += __shfl_xor(ssum, s);
  float invs = 1.0f / ssum;
  // PV: p in registers, v coalesced; reduced-shuffle epilogue
  float* obrow = ob + (size_t)(b * NSEL + i) * HDD + h * DKD;
  #pragma unroll
  for (int dp = 0; dp < 4; ++dp) {
    float acc[8] = {0.f, 0.f, 0.f, 0.f, 0.f, 0.f, 0.f, 0.f};
    #pragma unroll
    for (int u = 0; u < 8; ++u) {
      uint4 vv = vb4[dp * 512 + u * 64 + ln];
      float p = lg[u];
      acc[0] += p * BFL(vv.x); acc[1] += p * BFH(vv.x);
      acc[2] += p * BFL(vv.y); acc[3] += p * BFH(vv.y);
      acc[4] += p * BFL(vv.z); acc[5] += p * BFH(vv.z);
      acc[6] += p * BFL(vv.w); acc[7] += p * BFH(vv.w);
    }
    // octet-reduce all 8 accs (stages 1,2,4)
    #pragma unroll
    for (int s = 1; s < 8; s <<= 1) {
      #pragma unroll
      for (int t = 0; t < 8; ++t) acc[t] += __shfl_xor(acc[t], s);
    }
    // lane picks its d = ln&7, then cross-octet reduce (stages 8,16,32)
    int sel = ln & 7;
    float y = acc[0];
    #pragma unroll
    for (int t = 1; t < 8; ++t) y = (sel == t) ? acc[t] : y;
    #pragma unroll
    for (int s = 8; s < 64; s <<= 1) y += __shfl_xor(y, s);
    if (ln < 8) obrow[dp * 8 + ln] = y * invs;
  }
}

// ---------------- K5: fused proj+res+LN2+MLP+res (1 row/block) + qkv(l+1) ---
// grid 1024 -> 4 blocks/CU, 16 waves/CU (was 512/2-row at 8 waves/CU):
// weight L2 traffic doubles (~4us BW floor) but latency hiding doubles —
// same trade that paid off for qkv in R7.
__global__ __launch_bounds__(256) void mlpqkv_kernel(
    const float* __restrict__ ob, const float* __restrict__ Wo,
    const float* __restrict__ bo,
    const float* __restrict__ ln2_g, const float* __restrict__ ln2_b,
    const float* __restrict__ W1, const float* __restrict__ b1,
    const float* __restrict__ W2, const float* __restrict__ b2,
    const float* __restrict__ ln1_g, const float* __restrict__ ln1_b,
    const float* __restrict__ Wq, const float* __restrict__ Wk,
    const float* __restrict__ Wv, const float* __restrict__ Wrel,
    const float* __restrict__ rcb, const float* __restrict__ rpb,
    const int* __restrict__ idx, float* __restrict__ emb,
    float* __restrict__ qc, unsigned short* __restrict__ kbT,
    unsigned short* __restrict__ vT, float* __restrict__ wb,
    float* __restrict__ out, int layer) {
  __shared__ float part[8][32];
  __shared__ float res[32];
  __shared__ float hln[32];
  __shared__ float fin[32];
  __shared__ float a1s[MLPD];
  __shared__ float qs[128];
  int row = blockIdx.x;
  int b = row >> 9, ii = row & 511;
  int tid = threadIdx.x;
  int c = tid & 31, seg = tid >> 5;
  const float* wo = Wo + (size_t)layer * HDD * CCH + c;
  const float* orow = ob + (size_t)row * HDD;
  float pacc = 0.f;
  #pragma unroll
  for (int k = 0; k < 16; ++k) {
    int kk = seg * 16 + k;
    pacc += orow[kk] * wo[kk * CCH];
  }
  part[seg][c] = pacc;
  __syncthreads();
  if (tid < 32) {
    float s = bo[layer * CCH + tid] + emb[(size_t)row * CCH + tid];
    #pragma unroll
    for (int sg = 0; sg < 8; ++sg) s += part[sg][tid];
    res[tid] = s;
  }
  __syncthreads();
  if (tid < 32) {
    float mu = 0.f, s2 = 0.f;
    #pragma unroll
    for (int c2 = 0; c2 < 32; ++c2) { float v = res[c2]; mu += v; s2 += v * v; }
    mu *= (1.0f / 32.0f);
    float var = s2 * (1.0f / 32.0f) - mu * mu;
    float rstd = rsqrtf(var + 1e-5f);
    hln[tid] = (res[tid] - mu) * rstd * ln2_g[layer * CCH + tid] + ln2_b[layer * CCH + tid];
  }
  __syncthreads();
  const float* w1 = W1 + (size_t)layer * CCH * MLPD;
  float accA = b1[layer * MLPD + tid];
  float accB = b1[layer * MLPD + tid + 256];
  for (int c2 = 0; c2 < 32; ++c2) {
    float hv = hln[c2];
    accA += hv * w1[c2 * MLPD + tid];
    accB += hv * w1[c2 * MLPD + tid + 256];
  }
  a1s[tid]       = 0.5f * accA * (1.0f + erff(accA * 0.70710678118654752f));
  a1s[tid + 256] = 0.5f * accB * (1.0f + erff(accB * 0.70710678118654752f));
  __syncthreads();
  const float* w2 = W2 + (size_t)layer * MLPD * CCH;
  float acc2 = 0.f;
  #pragma unroll 4
  for (int mi = 0; mi < 64; ++mi) {
    int m = seg * 64 + mi;
    acc2 += a1s[m] * w2[m * CCH + c];
  }
  __syncthreads();                    // part[] reuse
  part[seg][c] = acc2;
  __syncthreads();
  if (tid < 32) {
    float s = b2[layer * CCH + tid] + res[tid];
    #pragma unroll
    for (int sg = 0; sg < 8; ++sg) s += part[sg][tid];
    fin[tid] = s;
    if (layer < 3) emb[(size_t)row * CCH + tid] = s;
  }
  __syncthreads();
  if (layer == 3) {
    if (tid < 32) {
      int li = idx[b * NSEL + ii];
      out[((size_t)b * CCH + tid) * SEQL + li] = fin[tid];
    }
    return;
  }
  const int l1 = layer + 1;
  bool act = tid < 128;
  int hd = tid & 127;
  int hh = hd >> 5, d = hd & 31;
  if (act) {
    float h[32];
    float mu = 0.f;
    #pragma unroll
    for (int c2 = 0; c2 < 32; ++c2) { h[c2] = fin[c2]; mu += h[c2]; }
    mu *= (1.0f / 32.0f);
    float var = 0.f;
    #pragma unroll
    for (int c2 = 0; c2 < 32; ++c2) { float dd = h[c2] - mu; var += dd * dd; }
    var *= (1.0f / 32.0f);
    float rstd = rsqrtf(var + 1e-5f);
    const float* g = ln1_g + l1 * CCH;
    const float* bb = ln1_b + l1 * CCH;
    #pragma unroll
    for (int c2 = 0; c2 < 32; ++c2) h[c2] = (h[c2] - mu) * rstd * g[c2] + bb[c2];
    const float* wq = Wq + (size_t)l1 * CCH * HDD + hd;
    const float* wk = Wk + (size_t)l1 * CCH * HDD + hd;
    const float* wv = Wv + (size_t)l1 * CCH * HDD + hd;
    float q = 0.f, kk = 0.f, vv = 0.f;
    #pragma unroll
    for (int c2 = 0; c2 < 32; ++c2) {
      q += h[c2] * wq[c2 * HDD];
      kk += h[c2] * wk[c2 * HDD];
      vv += h[c2] * wv[c2 * HDD];
    }
    q *= 0.17677669529663687f;
    qs[hd] = q;
    qc[(size_t)row * HDD + hd] = q + rcb[(l1 * NHEAD + hh) * DKD + d];
    size_t tpos = ((size_t)(b * 4 + hh) * 4 + (d >> 3)) * 4096 + (size_t)ii * 8 + (d & 7);
    kbT[tpos] = f2bf(kk);
    vT[tpos]  = f2bf(vv);
  }
  __syncthreads();
  if (act && hd < 120) {
    int h2 = hd / 30, f = hd % 30;
    const float* rp = rpb + (l1 * NHEAD + h2) * DKD;
    const float* wr = Wrel + ((size_t)l1 * 30 + f) * HDD + h2 * DKD;
    const float* qsh = qs + h2 * DKD;
    float acc = 0.f;
    #pragma unroll
    for (int dd = 0; dd < 32; ++dd) acc += (qsh[dd] + rp[dd]) * wr[dd];
    wb[((size_t)row * NHEAD + h2) * 32 + f] = acc;
  }
}

extern "C" void kernel_launch(void* const* d_in, const int* in_sizes, int n_in,
                              void* d_out, int out_size, void* d_ws, size_t ws_size,
                              hipStream_t stream) {
  (void)in_sizes; (void)n_in; (void)ws_size; (void)out_size;
  const float* x_skip    = (const float*)d_in[0];
  const float* attention = (const float*)d_in[1];
  const float* ln1_g = (const float*)d_in[2];
  const float* ln1_b = (const float*)d_in[3];
  const float* Wq    = (const float*)d_in[4];
  const float* Wk    = (const float*)d_in[5];
  const float* Wv    = (const float*)d_in[6];
  const float* Wrel  = (const float*)d_in[7];
  const float* rcb   = (const float*)d_in[8];
  const float* rpb   = (const float*)d_in[9];
  const float* Wo    = (const float*)d_in[10];
  const float* bo    = (const float*)d_in[11];
  const float* ln2_g = (const float*)d_in[12];
  const float* ln2_b = (const float*)d_in[13];
  const float* W1    = (const float*)d_in[14];
  const float* b1    = (const float*)d_in[15];
  const float* W2    = (const float*)d_in[16];
  const float* b2    = (const float*)d_in[17];
  float* out = (float*)d_out;
  char* ws = (char*)d_ws;

  unsigned char* E = (unsigned char*)(ws + 0);        // 45000*16 = 720,000
  int*      idx   = (int*)(ws + 1441792);             // 4,096
  float*    emb   = (float*)(ws + 1445888);           // 131,072
  float*    qc    = (float*)(ws + 1576960);           // 524,288
  unsigned short* kbT = (unsigned short*)(ws + 2101248); // 262,144
  unsigned short* vT  = (unsigned short*)(ws + 2363392); // 262,144
  float*    wb    = (float*)(ws + 2625536);           // 524,288
  float*    ob    = (float*)(ws + 3149824);           // 524,288
  int*      hist  = (int*)(ws + 3674112);             // 1,048,576
  int*      cnt   = (int*)(ws + 4722688);             // 16
  unsigned long long* cand = (unsigned long long*)(ws + 4722720); // 65,536
  unsigned* chsel = (unsigned*)(ws + 4788256);        // 4,096

  hipMemsetAsync(ws + 3674112, 0, 1048576 + 32, stream);   // hist + cnt
  prep_kernel<<<ETB + 4 * TKB, 256, 0, stream>>>(attention, E, hist, out);
  topk_collect_kernel<<<4 * TKB, 256, 0, stream>>>(attention, hist, cand, cnt);
  topk_sort_kernel<<<4, 1024, 0, stream>>>(cand, cnt, chsel);
  topk_merge_kernel<<<2, 512, 0, stream>>>(chsel, idx);
  gqkv0_kernel<<<1024, 128, 0, stream>>>(x_skip, idx, ln1_g, ln1_b, Wq, Wk, Wv,
                                         Wrel, rcb, rpb, emb, qc, kbT, vT, wb);
  for (int l = 0; l < 4; ++l) {
    attn_kernel<<<1024, 256, 0, stream>>>(qc, kbT, vT, wb, E, idx, ob);
    mlpqkv_kernel<<<1024, 256, 0, stream>>>(ob, Wo, bo, ln2_g, ln2_b, W1, b1,
                                            W2, b2, ln1_g, ln1_b, Wq, Wk, Wv,
                                            Wrel, rcb, rpb, idx, emb, qc, kbT,
                                            vT, wb, out, l);
  }
}